// Round 4
// baseline (250.359 us; speedup 1.0000x reference)
//
#include <hip/hip_runtime.h>

#define NH 8
#define HD 32
#define NL 4
#define NP 4
#define DM 256
#define LEN_IN_C 13294
#define LQ_C 13294
#define B_C 2
#define M_TOTAL (B_C * LQ_C)           // 26588
#define MT_TILES 1662                  // ceil(26588/16)

typedef __attribute__((ext_vector_type(8))) short short8;
typedef __attribute__((ext_vector_type(4))) float floatx4;

__device__ __forceinline__ unsigned short f2bf(float x) {
    union { float f; unsigned int u; } a; a.f = x;
    unsigned int r = (a.u + 0x7FFFu + ((a.u >> 16) & 1u)) >> 16;
    return (unsigned short)r;
}
__device__ __forceinline__ float bflo(unsigned int u) {
    union { unsigned int u; float f; } a; a.u = u << 16; return a.f;
}
__device__ __forceinline__ float bfhi(unsigned int u) {
    union { unsigned int u; float f; } a; a.u = u & 0xffff0000u; return a.f;
}

// pack 8 fp32 -> 8 bf16 (round-half-up) using v_perm
__device__ __forceinline__ short8 pack_bf16_8(float4 f0, float4 f1) {
    const unsigned a0 = __float_as_uint(f0.x) + 0x8000u;
    const unsigned a1 = __float_as_uint(f0.y) + 0x8000u;
    const unsigned a2 = __float_as_uint(f0.z) + 0x8000u;
    const unsigned a3 = __float_as_uint(f0.w) + 0x8000u;
    const unsigned b0 = __float_as_uint(f1.x) + 0x8000u;
    const unsigned b1 = __float_as_uint(f1.y) + 0x8000u;
    const unsigned b2 = __float_as_uint(f1.z) + 0x8000u;
    const unsigned b3 = __float_as_uint(f1.w) + 0x8000u;
    union { unsigned u[4]; short8 s; } r;
    r.u[0] = __builtin_amdgcn_perm(a1, a0, 0x07060302);
    r.u[1] = __builtin_amdgcn_perm(a3, a2, 0x07060302);
    r.u[2] = __builtin_amdgcn_perm(b1, b0, 0x07060302);
    r.u[3] = __builtin_amdgcn_perm(b3, b2, 0x07060302);
    return r.s;
}

__device__ __forceinline__ void conv_b_body(const float* __restrict__ W,
                                            unsigned short* __restrict__ Bsw,
                                            int Nsrc, int NTsrc, int NTtotal, int ntOff,
                                            int vblk) {
    const int u = vblk * 256 + threadIdx.x;
    const int lane = u & 63;
    const int unit = u >> 6;
    const int ntl = unit % NTsrc;
    const int kc = unit / NTsrc;
    const int n = ntl * 16 + (lane & 15);
    const int k0 = kc * 32 + (lane >> 4) * 8;
    short8 v;
#pragma unroll
    for (int j = 0; j < 8; ++j)
        v[j] = (short)f2bf(W[(size_t)(k0 + j) * Nsrc + n]);
    ((short8*)Bsw)[(size_t)(kc * NTtotal + ntOff + ntl) * 64 + lane] = v;
}

__global__ __launch_bounds__(256) void conv_weights_kernel(const float* __restrict__ Wv,
                                                           const float* __restrict__ Woff,
                                                           const float* __restrict__ Wattn,
                                                           const float* __restrict__ Wout,
                                                           const float* __restrict__ boff,
                                                           const float* __restrict__ battn,
                                                           unsigned short* __restrict__ BswV,
                                                           unsigned short* __restrict__ BswOA,
                                                           unsigned short* __restrict__ BswO,
                                                           float* __restrict__ fbias) {
    const int blk = blockIdx.x;
    if (blk < 32)        conv_b_body(Wv,    BswV,  256, 16, 16, 0,  blk);
    else if (blk < 64)   conv_b_body(Woff,  BswOA, 256, 16, 24, 0,  blk - 32);
    else if (blk < 80)   conv_b_body(Wattn, BswOA, 128,  8, 24, 16, blk - 64);
    else if (blk < 112)  conv_b_body(Wout,  BswO,  256, 16, 16, 0,  blk - 80);
    else {
        const int t = (blk - 112) * 256 + threadIdx.x;
        if (t < 384) fbias[t] = (t < 256) ? boff[t] : battn[t - 256];
    }
}

// ---------------------------------------------------------------------------
// GEMM body: 1 row-tile per block, software-prefetched kc loop.
// ---------------------------------------------------------------------------
template <int NT, bool OUT_BF16, bool A_F32>
__device__ __forceinline__ void gemm_body(const void* __restrict__ Aptr,
                                          const short8* __restrict__ Bu,
                                          const float* __restrict__ bias,
                                          void* __restrict__ Cout, int M, int rt) {
    constexpr int NTW = NT / 4;
    const int tid = threadIdx.x;
    const int lane = tid & 63;
    const int wave = tid >> 6;

    const int m = lane & 15;
    const int q = lane >> 4;
    int arow = rt * 16 + m; if (arow >= M) arow = M - 1;
    const float* ap = (const float*)Aptr + (size_t)arow * 256 + q * 8;
    const short8* Au = (const short8*)Aptr;

    floatx4 acc[NTW];
#pragma unroll
    for (int t = 0; t < NTW; ++t) acc[t] = (floatx4){0.f, 0.f, 0.f, 0.f};

    short8 a_cur, a_nxt;
    short8 b_cur[NTW], b_nxt[NTW];

    if (A_F32) {
        const float4 f0 = *(const float4*)(ap);
        const float4 f1 = *(const float4*)(ap + 4);
        a_cur = pack_bf16_8(f0, f1);
    } else {
        a_cur = Au[(size_t)(rt * 8 + 0) * 64 + lane];
    }
#pragma unroll
    for (int t = 0; t < NTW; ++t)
        b_cur[t] = Bu[(size_t)(wave * NTW + t) * 64 + lane];

#pragma unroll
    for (int kc = 0; kc < 8; ++kc) {
        if (kc < 7) {
            if (A_F32) {
                const float4 f0 = *(const float4*)(ap + (kc + 1) * 32);
                const float4 f1 = *(const float4*)(ap + (kc + 1) * 32 + 4);
                a_nxt = pack_bf16_8(f0, f1);
            } else {
                a_nxt = Au[(size_t)(rt * 8 + kc + 1) * 64 + lane];
            }
#pragma unroll
            for (int t = 0; t < NTW; ++t)
                b_nxt[t] = Bu[(size_t)((kc + 1) * NT + wave * NTW + t) * 64 + lane];
        }
#pragma unroll
        for (int t = 0; t < NTW; ++t)
            acc[t] = __builtin_amdgcn_mfma_f32_16x16x32_bf16(a_cur, b_cur[t], acc[t], 0, 0, 0);
        if (kc < 7) {
            a_cur = a_nxt;
#pragma unroll
            for (int t = 0; t < NTW; ++t) b_cur[t] = b_nxt[t];
        }
    }

    const int N = NT * 16;
    const int colq = lane & 15;
    const int rowq = (lane >> 4) * 4;
#pragma unroll
    for (int t = 0; t < NTW; ++t) {
        const int col = (wave * NTW + t) * 16 + colq;
        const float bc = bias[col];
#pragma unroll
        for (int reg = 0; reg < 4; ++reg) {
            const int row = rt * 16 + rowq + reg;
            if (row < M) {
                const float v = acc[t][reg] + bc;
                if (OUT_BF16)
                    ((unsigned short*)Cout)[(size_t)row * N + col] = f2bf(v);
                else
                    ((float*)Cout)[(size_t)row * N + col] = v;
            }
        }
    }
}

__global__ __launch_bounds__(256, 4) void dual_gemm_kernel(const float* __restrict__ inflat,
                                                           const float* __restrict__ query,
                                                           const short8* __restrict__ BuV,
                                                           const short8* __restrict__ BuOA,
                                                           const float* __restrict__ bv,
                                                           const float* __restrict__ fbias,
                                                           unsigned short* __restrict__ value,
                                                           float* __restrict__ fused, int M) {
    if (blockIdx.x < MT_TILES)
        gemm_body<16, true, true>(inflat, BuV, bv, value, M, blockIdx.x);
    else
        gemm_body<24, false, true>(query, BuOA, fbias, fused, M, blockIdx.x - MT_TILES);
}

__global__ __launch_bounds__(256, 4) void out_gemm_kernel(const unsigned short* __restrict__ AccSw,
                                                          const short8* __restrict__ BuO,
                                                          const float* __restrict__ bout,
                                                          float* __restrict__ out, int M) {
    gemm_body<16, false, false>(AccSw, BuO, bout, out, M, blockIdx.x);
}

// ---------------------------------------------------------------------------
// Sampler (see header comments in previous rounds). Phase 2 uses group-of-4
// point batching: 16 independent uint2 loads in flight before consumption.
// ---------------------------------------------------------------------------
__global__ __launch_bounds__(256, 4) void msda_sample_kernel(const float* __restrict__ refp,
                                                             const unsigned short* __restrict__ value,
                                                             const float* __restrict__ fused,
                                                             unsigned short* __restrict__ AccSw) {
    constexpr int lvl_hw[4] = {100, 50, 25, 13};
    constexpr int lvl_s[4] = {0, 10000, 12500, 13125};

    const int bq0 = blockIdx.x * 4;
    const int tid = threadIdx.x;

    __shared__ float s_ref[32];
    __shared__ int4 s_pi[4 * 8 * 17];
    __shared__ float4 s_pw[4 * 8 * 17];

    if (tid < 32) s_ref[tid] = refp[(size_t)bq0 * 8 + tid];
    __syncthreads();

#pragma unroll
    for (int jj = 0; jj < 2; ++jj) {
        const int job = jj * 256 + tid;
        const int qq = job >> 7;
        const int t = job & 127;
        const int h = t >> 4;
        const int l = (t >> 2) & 3;
        const int bq = bq0 + qq;
        const int b = (bq >= LQ_C) ? 1 : 0;

        const float logit = fused[(size_t)bq * 384 + 256 + t];
        float mx = logit;
#pragma unroll
        for (int mask = 1; mask < 16; mask <<= 1) mx = fmaxf(mx, __shfl_xor(mx, mask));
        const float e = expf(logit - mx);
        float s = e;
#pragma unroll
        for (int mask = 1; mask < 16; mask <<= 1) s += __shfl_xor(s, mask);
        const float aw = e / s;

        const int whl = lvl_hw[l];
        const float fwh = (float)whl;
        const float2 oxy = *(const float2*)(fused + (size_t)bq * 384 + t * 2);
        const float x = s_ref[qq * 8 + l * 2] * fwh + oxy.x - 0.5f;
        const float y = s_ref[qq * 8 + l * 2 + 1] * fwh + oxy.y - 0.5f;
        const float x0f = floorf(x), y0f = floorf(y);
        const float tx = x - x0f, ty = y - y0f;
        const int ix0 = (int)x0f, iy0 = (int)y0f;

        const bool xv0 = (unsigned)ix0 < (unsigned)whl;
        const bool xv1 = (unsigned)(ix0 + 1) < (unsigned)whl;
        const bool yv0 = (unsigned)iy0 < (unsigned)whl;
        const bool yv1 = (unsigned)(iy0 + 1) < (unsigned)whl;

        const int cx0 = min(max(ix0, 0), whl - 1);
        const int cx1 = min(max(ix0 + 1, 0), whl - 1);
        const int cy0 = min(max(iy0, 0), whl - 1);
        const int cy1 = min(max(iy0 + 1, 0), whl - 1);

        const int base = (b * LEN_IN_C + lvl_s[l]) * 256 + h * 32;
        const int r0 = base + cy0 * (whl * 256);
        const int r1 = base + cy1 * (whl * 256);
        int4 ii;
        ii.x = (r0 + cx0 * 256) * 2;
        ii.y = (r0 + cx1 * 256) * 2;
        ii.z = (r1 + cx0 * 256) * 2;
        ii.w = (r1 + cx1 * 256) * 2;
        float4 wv;
        wv.x = (xv0 && yv0) ? aw * (1.f - tx) * (1.f - ty) : 0.f;
        wv.y = (xv1 && yv0) ? aw * tx * (1.f - ty) : 0.f;
        wv.z = (xv0 && yv1) ? aw * (1.f - tx) * ty : 0.f;
        wv.w = (xv1 && yv1) ? aw * tx * ty : 0.f;
        const int slot = (qq * 8 + h) * 17 + (t & 15);
        s_pi[slot] = ii;
        s_pw[slot] = wv;
    }
    __syncthreads();

    const int qq = tid >> 6;
    const int h = (tid >> 3) & 7;
    const int l8 = tid & 7;
    const char* vbp = (const char*)value + l8 * 8;
    const int pbase = (qq * 8 + h) * 17;

    float4 acc0 = {0.f, 0.f, 0.f, 0.f};
    float4 acc1 = {0.f, 0.f, 0.f, 0.f};
#pragma unroll
    for (int g = 0; g < 4; ++g) {
        int4 ii[4]; float4 ww[4]; uint2 v[16];
#pragma unroll
        for (int p = 0; p < 4; ++p) {
            ii[p] = s_pi[pbase + g * 4 + p];
            ww[p] = s_pw[pbase + g * 4 + p];
        }
#pragma unroll
        for (int p = 0; p < 4; ++p) {
            v[p * 4 + 0] = *(const uint2*)(vbp + ii[p].x);
            v[p * 4 + 1] = *(const uint2*)(vbp + ii[p].y);
            v[p * 4 + 2] = *(const uint2*)(vbp + ii[p].z);
            v[p * 4 + 3] = *(const uint2*)(vbp + ii[p].w);
        }
#pragma unroll
        for (int p = 0; p < 4; ++p) {
            const float4 wv = ww[p];
            const uint2 v00 = v[p * 4 + 0], v01 = v[p * 4 + 1];
            const uint2 v10 = v[p * 4 + 2], v11 = v[p * 4 + 3];
            acc0.x += wv.x * bflo(v00.x); acc0.y += wv.x * bfhi(v00.x);
            acc0.z += wv.x * bflo(v00.y); acc0.w += wv.x * bfhi(v00.y);
            acc1.x += wv.y * bflo(v01.x); acc1.y += wv.y * bfhi(v01.x);
            acc1.z += wv.y * bflo(v01.y); acc1.w += wv.y * bfhi(v01.y);
            acc0.x += wv.z * bflo(v10.x); acc0.y += wv.z * bfhi(v10.x);
            acc0.z += wv.z * bflo(v10.y); acc0.w += wv.z * bfhi(v10.y);
            acc1.x += wv.w * bflo(v11.x); acc1.y += wv.w * bfhi(v11.x);
            acc1.z += wv.w * bflo(v11.y); acc1.w += wv.w * bfhi(v11.y);
        }
    }
    const float4 acc = {acc0.x + acc1.x, acc0.y + acc1.y, acc0.z + acc1.z, acc0.w + acc1.w};

    const int bq = bq0 + qq;
    const int rt = bq >> 4, mm = bq & 15;
    const int col = h * 32 + l8 * 4;
    const int kc = col >> 5, q2 = (col >> 3) & 3, j = col & 7;
    unsigned int p0 = (unsigned int)f2bf(acc.x) | ((unsigned int)f2bf(acc.y) << 16);
    unsigned int p1 = (unsigned int)f2bf(acc.z) | ((unsigned int)f2bf(acc.w) << 16);
    uint2 pk; pk.x = p0; pk.y = p1;
    *(uint2*)(AccSw + ((size_t)((rt * 8 + kc) * 64 + (q2 * 16 + mm)) * 8 + j)) = pk;
}

extern "C" void kernel_launch(void* const* d_in, const int* in_sizes, int n_in,
                              void* d_out, int out_size, void* d_ws, size_t ws_size,
                              hipStream_t stream) {
    const float* query  = (const float*)d_in[0];
    const float* refp   = (const float*)d_in[1];
    const float* inflat = (const float*)d_in[2];
    const float* Wv    = (const float*)d_in[4];
    const float* bv    = (const float*)d_in[5];
    const float* Woff  = (const float*)d_in[6];
    const float* boff  = (const float*)d_in[7];
    const float* Wattn = (const float*)d_in[8];
    const float* battn = (const float*)d_in[9];
    const float* Wout  = (const float*)d_in[10];
    const float* bout  = (const float*)d_in[11];
    float* out = (float*)d_out;

    char* p = (char*)d_ws;
    const size_t aswBytes = (size_t)MT_TILES * 8 * 64 * 8 * sizeof(unsigned short);
    unsigned short* AccSw = (unsigned short*)p;          p += aswBytes;
    unsigned short* BswV = (unsigned short*)p;           p += (size_t)8 * 16 * 64 * 8 * 2;
    unsigned short* BswOA = (unsigned short*)p;          p += (size_t)8 * 24 * 64 * 8 * 2;
    unsigned short* BswO = (unsigned short*)p;           p += (size_t)8 * 16 * 64 * 8 * 2;
    float* fbias = (float*)p;                            p += 384 * sizeof(float);
    unsigned short* value = (unsigned short*)p;          p += (size_t)M_TOTAL * 256 * 2;
    float* fused = (float*)p;                            p += (size_t)M_TOTAL * 384 * 4;

    const int M = M_TOTAL;

    conv_weights_kernel<<<114, 256, 0, stream>>>(Wv, Woff, Wattn, Wout, boff, battn,
                                                 BswV, BswOA, BswO, fbias);
    dual_gemm_kernel<<<MT_TILES * 2, 256, 0, stream>>>(inflat, query,
                                                       (const short8*)BswV, (const short8*)BswOA,
                                                       bv, fbias, value, fused, M);
    msda_sample_kernel<<<M / 4, 256, 0, stream>>>(refp, value, fused, AccSw);
    out_gemm_kernel<<<MT_TILES, 256, 0, stream>>>(AccSw, (const short8*)BswO, bout, out, M);
}

// Round 5
// 231.683 us; speedup vs baseline: 1.0806x; 1.0806x over previous
//
#include <hip/hip_runtime.h>

#define NH 8
#define HD 32
#define NL 4
#define NP 4
#define DM 256
#define LEN_IN_C 13294
#define LQ_C 13294
#define B_C 2
#define M_TOTAL (B_C * LQ_C)           // 26588
#define MT_TILES 1662                  // ceil(26588/16)

typedef __attribute__((ext_vector_type(8))) short short8;
typedef __attribute__((ext_vector_type(4))) float floatx4;

__device__ __forceinline__ unsigned short f2bf(float x) {
    union { float f; unsigned int u; } a; a.f = x;
    unsigned int r = (a.u + 0x7FFFu + ((a.u >> 16) & 1u)) >> 16;
    return (unsigned short)r;
}
__device__ __forceinline__ float bflo(unsigned int u) {
    union { unsigned int u; float f; } a; a.u = u << 16; return a.f;
}
__device__ __forceinline__ float bfhi(unsigned int u) {
    union { unsigned int u; float f; } a; a.u = u & 0xffff0000u; return a.f;
}

// ---------------------------------------------------------------------------
// Convert A [M,256] fp32 row-major -> swizzled bf16 fragments.
// Unit u = (rt*8 + kc)*64 + lane; lane = m + 16*q holds A[rt*16+m][kc*32+q*8+j].
// grid.y selects (A0->D0) or (A1->D1). grid.x = MT_TILES*2 (exactly 850944 thr).
// ---------------------------------------------------------------------------
__global__ __launch_bounds__(256) void conv_a_kernel(const float* __restrict__ A0,
                                                     unsigned short* __restrict__ D0,
                                                     const float* __restrict__ A1,
                                                     unsigned short* __restrict__ D1,
                                                     int M) {
    const float* A = blockIdx.y ? A1 : A0;
    unsigned short* Asw = blockIdx.y ? D1 : D0;
    const int u = blockIdx.x * 256 + threadIdx.x;
    const int lane = u & 63;
    const int kc = (u >> 6) & 7;
    const int rt = u >> 9;
    const int row = rt * 16 + (lane & 15);
    const int col0 = kc * 32 + (lane >> 4) * 8;
    unsigned short tmp[8];
    if (row < M) {
        const float4 f0 = *(const float4*)(A + (size_t)row * 256 + col0);
        const float4 f1 = *(const float4*)(A + (size_t)row * 256 + col0 + 4);
        tmp[0] = f2bf(f0.x); tmp[1] = f2bf(f0.y); tmp[2] = f2bf(f0.z); tmp[3] = f2bf(f0.w);
        tmp[4] = f2bf(f1.x); tmp[5] = f2bf(f1.y); tmp[6] = f2bf(f1.z); tmp[7] = f2bf(f1.w);
    } else {
#pragma unroll
        for (int j = 0; j < 8; ++j) tmp[j] = 0;
    }
    short8 v;
#pragma unroll
    for (int j = 0; j < 8; ++j) v[j] = (short)tmp[j];
    ((short8*)Asw)[u] = v;
}

// ---------------------------------------------------------------------------
// All weight conversions + bias fuse in ONE kernel.
// ---------------------------------------------------------------------------
__device__ __forceinline__ void conv_b_body(const float* __restrict__ W,
                                            unsigned short* __restrict__ Bsw,
                                            int Nsrc, int NTsrc, int NTtotal, int ntOff,
                                            int vblk) {
    const int u = vblk * 256 + threadIdx.x;
    const int lane = u & 63;
    const int unit = u >> 6;
    const int ntl = unit % NTsrc;
    const int kc = unit / NTsrc;
    const int n = ntl * 16 + (lane & 15);
    const int k0 = kc * 32 + (lane >> 4) * 8;
    short8 v;
#pragma unroll
    for (int j = 0; j < 8; ++j)
        v[j] = (short)f2bf(W[(size_t)(k0 + j) * Nsrc + n]);
    ((short8*)Bsw)[(size_t)(kc * NTtotal + ntOff + ntl) * 64 + lane] = v;
}

__global__ __launch_bounds__(256) void conv_weights_kernel(const float* __restrict__ Wv,
                                                           const float* __restrict__ Woff,
                                                           const float* __restrict__ Wattn,
                                                           const float* __restrict__ Wout,
                                                           const float* __restrict__ boff,
                                                           const float* __restrict__ battn,
                                                           unsigned short* __restrict__ BswV,
                                                           unsigned short* __restrict__ BswOA,
                                                           unsigned short* __restrict__ BswO,
                                                           float* __restrict__ fbias) {
    const int blk = blockIdx.x;
    if (blk < 32)        conv_b_body(Wv,    BswV,  256, 16, 16, 0,  blk);
    else if (blk < 64)   conv_b_body(Woff,  BswOA, 256, 16, 24, 0,  blk - 32);
    else if (blk < 80)   conv_b_body(Wattn, BswOA, 128,  8, 24, 16, blk - 64);
    else if (blk < 112)  conv_b_body(Wout,  BswO,  256, 16, 16, 0,  blk - 80);
    else {
        const int t = (blk - 112) * 256 + threadIdx.x;
        if (t < 384) fbias[t] = (t < 256) ? boff[t] : battn[t - 256];
    }
}

// ---------------------------------------------------------------------------
// Full-K register-unrolled GEMM body. One row-tile per block (4 waves).
// Wave covers NTW n-tiles starting at ntBase. ALL 8+8*NTW fragment loads are
// issued up front (independent 16B loads); 8*NTW MFMAs consume in issue order.
// One latency exposure per wave instead of 8.
// ---------------------------------------------------------------------------
template <int NTW, bool OUT_BF16>
__device__ __forceinline__ void gemm_body_fk(const short8* __restrict__ Au,
                                             const short8* __restrict__ Bu,
                                             int ntBase, int NT_B,
                                             const float* __restrict__ bias,
                                             void* __restrict__ Cout, int Ncols,
                                             int M, int rt) {
    const int lane = threadIdx.x & 63;

    short8 a[8];
    short8 b[8][NTW];
#pragma unroll
    for (int kc = 0; kc < 8; ++kc) {
        a[kc] = Au[(size_t)(rt * 8 + kc) * 64 + lane];
#pragma unroll
        for (int t = 0; t < NTW; ++t)
            b[kc][t] = Bu[(size_t)(kc * NT_B + ntBase + t) * 64 + lane];
    }

    floatx4 acc[NTW];
#pragma unroll
    for (int t = 0; t < NTW; ++t) acc[t] = (floatx4){0.f, 0.f, 0.f, 0.f};

#pragma unroll
    for (int kc = 0; kc < 8; ++kc)
#pragma unroll
        for (int t = 0; t < NTW; ++t)
            acc[t] = __builtin_amdgcn_mfma_f32_16x16x32_bf16(a[kc], b[kc][t], acc[t], 0, 0, 0);

    const int colq = lane & 15;
    const int rowq = (lane >> 4) * 4;
#pragma unroll
    for (int t = 0; t < NTW; ++t) {
        const int col = (ntBase + t) * 16 + colq;
        const float bc = bias[col];
#pragma unroll
        for (int reg = 0; reg < 4; ++reg) {
            const int row = rt * 16 + rowq + reg;
            if (row < M) {
                const float v = acc[t][reg] + bc;
                if (OUT_BF16)
                    ((unsigned short*)Cout)[(size_t)row * Ncols + col] = f2bf(v);
                else
                    ((float*)Cout)[(size_t)row * Ncols + col] = v;
            }
        }
    }
}

// value-GEMM + fused offs/attn-GEMM in one launch.
// blocks [0,MT): value (NTW=4, N=256); [MT,2MT): fused cols 0..255 (NTW=4);
// [2MT,3MT): fused cols 256..383 (NTW=2).
__global__ __launch_bounds__(256, 2) void dual_gemm_kernel(const short8* __restrict__ AuV,
                                                           const short8* __restrict__ AuQ,
                                                           const short8* __restrict__ BuV,
                                                           const short8* __restrict__ BuOA,
                                                           const float* __restrict__ bv,
                                                           const float* __restrict__ fbias,
                                                           unsigned short* __restrict__ value,
                                                           float* __restrict__ fused, int M) {
    const int wave = (int)(threadIdx.x >> 6);
    const int bx = blockIdx.x;
    if (bx < MT_TILES)
        gemm_body_fk<4, true>(AuV, BuV, wave * 4, 16, bv, value, 256, M, bx);
    else if (bx < 2 * MT_TILES)
        gemm_body_fk<4, false>(AuQ, BuOA, wave * 4, 24, fbias, fused, 384, M, bx - MT_TILES);
    else
        gemm_body_fk<2, false>(AuQ, BuOA, 16 + wave * 2, 24, fbias, fused, 384, M, bx - 2 * MT_TILES);
}

__global__ __launch_bounds__(256, 2) void out_gemm_kernel(const short8* __restrict__ AuAcc,
                                                          const short8* __restrict__ BuO,
                                                          const float* __restrict__ bout,
                                                          float* __restrict__ out, int M) {
    const int wave = (int)(threadIdx.x >> 6);
    gemm_body_fk<4, false>(AuAcc, BuO, wave * 4, 16, bout, out, 256, M, blockIdx.x);
}

// ---------------------------------------------------------------------------
// Sampler (unchanged from R4): 4 queries/block; phase 1 computes softmax +
// premultiplied corner weights + byte offsets into LDS; phase 2 gathers with
// group-of-4 point batching (16 uint2 loads in flight).
// ---------------------------------------------------------------------------
__global__ __launch_bounds__(256, 4) void msda_sample_kernel(const float* __restrict__ refp,
                                                             const unsigned short* __restrict__ value,
                                                             const float* __restrict__ fused,
                                                             unsigned short* __restrict__ AccSw) {
    constexpr int lvl_hw[4] = {100, 50, 25, 13};
    constexpr int lvl_s[4] = {0, 10000, 12500, 13125};

    const int bq0 = blockIdx.x * 4;
    const int tid = threadIdx.x;

    __shared__ float s_ref[32];
    __shared__ int4 s_pi[4 * 8 * 17];
    __shared__ float4 s_pw[4 * 8 * 17];

    if (tid < 32) s_ref[tid] = refp[(size_t)bq0 * 8 + tid];
    __syncthreads();

#pragma unroll
    for (int jj = 0; jj < 2; ++jj) {
        const int job = jj * 256 + tid;
        const int qq = job >> 7;
        const int t = job & 127;
        const int h = t >> 4;
        const int l = (t >> 2) & 3;
        const int bq = bq0 + qq;
        const int b = (bq >= LQ_C) ? 1 : 0;

        const float logit = fused[(size_t)bq * 384 + 256 + t];
        float mx = logit;
#pragma unroll
        for (int mask = 1; mask < 16; mask <<= 1) mx = fmaxf(mx, __shfl_xor(mx, mask));
        const float e = expf(logit - mx);
        float s = e;
#pragma unroll
        for (int mask = 1; mask < 16; mask <<= 1) s += __shfl_xor(s, mask);
        const float aw = e / s;

        const int whl = lvl_hw[l];
        const float fwh = (float)whl;
        const float2 oxy = *(const float2*)(fused + (size_t)bq * 384 + t * 2);
        const float x = s_ref[qq * 8 + l * 2] * fwh + oxy.x - 0.5f;
        const float y = s_ref[qq * 8 + l * 2 + 1] * fwh + oxy.y - 0.5f;
        const float x0f = floorf(x), y0f = floorf(y);
        const float tx = x - x0f, ty = y - y0f;
        const int ix0 = (int)x0f, iy0 = (int)y0f;

        const bool xv0 = (unsigned)ix0 < (unsigned)whl;
        const bool xv1 = (unsigned)(ix0 + 1) < (unsigned)whl;
        const bool yv0 = (unsigned)iy0 < (unsigned)whl;
        const bool yv1 = (unsigned)(iy0 + 1) < (unsigned)whl;

        const int cx0 = min(max(ix0, 0), whl - 1);
        const int cx1 = min(max(ix0 + 1, 0), whl - 1);
        const int cy0 = min(max(iy0, 0), whl - 1);
        const int cy1 = min(max(iy0 + 1, 0), whl - 1);

        const int base = (b * LEN_IN_C + lvl_s[l]) * 256 + h * 32;
        const int r0 = base + cy0 * (whl * 256);
        const int r1 = base + cy1 * (whl * 256);
        int4 ii;
        ii.x = (r0 + cx0 * 256) * 2;
        ii.y = (r0 + cx1 * 256) * 2;
        ii.z = (r1 + cx0 * 256) * 2;
        ii.w = (r1 + cx1 * 256) * 2;
        float4 wv;
        wv.x = (xv0 && yv0) ? aw * (1.f - tx) * (1.f - ty) : 0.f;
        wv.y = (xv1 && yv0) ? aw * tx * (1.f - ty) : 0.f;
        wv.z = (xv0 && yv1) ? aw * (1.f - tx) * ty : 0.f;
        wv.w = (xv1 && yv1) ? aw * tx * ty : 0.f;
        const int slot = (qq * 8 + h) * 17 + (t & 15);
        s_pi[slot] = ii;
        s_pw[slot] = wv;
    }
    __syncthreads();

    const int qq = tid >> 6;
    const int h = (tid >> 3) & 7;
    const int l8 = tid & 7;
    const char* vbp = (const char*)value + l8 * 8;
    const int pbase = (qq * 8 + h) * 17;

    float4 acc0 = {0.f, 0.f, 0.f, 0.f};
    float4 acc1 = {0.f, 0.f, 0.f, 0.f};
#pragma unroll
    for (int g = 0; g < 4; ++g) {
        int4 ii[4]; float4 ww[4]; uint2 v[16];
#pragma unroll
        for (int p = 0; p < 4; ++p) {
            ii[p] = s_pi[pbase + g * 4 + p];
            ww[p] = s_pw[pbase + g * 4 + p];
        }
#pragma unroll
        for (int p = 0; p < 4; ++p) {
            v[p * 4 + 0] = *(const uint2*)(vbp + ii[p].x);
            v[p * 4 + 1] = *(const uint2*)(vbp + ii[p].y);
            v[p * 4 + 2] = *(const uint2*)(vbp + ii[p].z);
            v[p * 4 + 3] = *(const uint2*)(vbp + ii[p].w);
        }
#pragma unroll
        for (int p = 0; p < 4; ++p) {
            const float4 wv = ww[p];
            const uint2 v00 = v[p * 4 + 0], v01 = v[p * 4 + 1];
            const uint2 v10 = v[p * 4 + 2], v11 = v[p * 4 + 3];
            acc0.x += wv.x * bflo(v00.x); acc0.y += wv.x * bfhi(v00.x);
            acc0.z += wv.x * bflo(v00.y); acc0.w += wv.x * bfhi(v00.y);
            acc1.x += wv.y * bflo(v01.x); acc1.y += wv.y * bfhi(v01.x);
            acc1.z += wv.y * bflo(v01.y); acc1.w += wv.y * bfhi(v01.y);
            acc0.x += wv.z * bflo(v10.x); acc0.y += wv.z * bfhi(v10.x);
            acc0.z += wv.z * bflo(v10.y); acc0.w += wv.z * bfhi(v10.y);
            acc1.x += wv.w * bflo(v11.x); acc1.y += wv.w * bfhi(v11.x);
            acc1.z += wv.w * bflo(v11.y); acc1.w += wv.w * bfhi(v11.y);
        }
    }
    const float4 acc = {acc0.x + acc1.x, acc0.y + acc1.y, acc0.z + acc1.z, acc0.w + acc1.w};

    const int bq = bq0 + qq;
    const int rt = bq >> 4, mm = bq & 15;
    const int col = h * 32 + l8 * 4;
    const int kc = col >> 5, q2 = (col >> 3) & 3, j = col & 7;
    unsigned int p0 = (unsigned int)f2bf(acc.x) | ((unsigned int)f2bf(acc.y) << 16);
    unsigned int p1 = (unsigned int)f2bf(acc.z) | ((unsigned int)f2bf(acc.w) << 16);
    uint2 pk; pk.x = p0; pk.y = p1;
    *(uint2*)(AccSw + ((size_t)((rt * 8 + kc) * 64 + (q2 * 16 + mm)) * 8 + j)) = pk;
}

extern "C" void kernel_launch(void* const* d_in, const int* in_sizes, int n_in,
                              void* d_out, int out_size, void* d_ws, size_t ws_size,
                              hipStream_t stream) {
    const float* query  = (const float*)d_in[0];
    const float* refp   = (const float*)d_in[1];
    const float* inflat = (const float*)d_in[2];
    const float* Wv    = (const float*)d_in[4];
    const float* bv    = (const float*)d_in[5];
    const float* Woff  = (const float*)d_in[6];
    const float* boff  = (const float*)d_in[7];
    const float* Wattn = (const float*)d_in[8];
    const float* battn = (const float*)d_in[9];
    const float* Wout  = (const float*)d_in[10];
    const float* bout  = (const float*)d_in[11];
    float* out = (float*)d_out;

    char* p = (char*)d_ws;
    const size_t aswBytes = (size_t)MT_TILES * 8 * 64 * 8 * sizeof(unsigned short); // 13.6 MB
    unsigned short* AswV = (unsigned short*)p;           p += aswBytes;  // value A-frags, later AccSw
    unsigned short* AswQ = (unsigned short*)p;           p += aswBytes;
    unsigned short* BswV = (unsigned short*)p;           p += (size_t)8 * 16 * 64 * 8 * 2;
    unsigned short* BswOA = (unsigned short*)p;          p += (size_t)8 * 24 * 64 * 8 * 2;
    unsigned short* BswO = (unsigned short*)p;           p += (size_t)8 * 16 * 64 * 8 * 2;
    float* fbias = (float*)p;                            p += 384 * sizeof(float);
    unsigned short* value = (unsigned short*)p;          p += (size_t)M_TOTAL * 256 * 2;
    float* fused = (float*)p;                            p += (size_t)M_TOTAL * 384 * 4;
    unsigned short* AccSw = AswV;   // alias: dual consumes AswV before sampler writes

    const int M = M_TOTAL;

    conv_weights_kernel<<<114, 256, 0, stream>>>(Wv, Woff, Wattn, Wout, boff, battn,
                                                 BswV, BswOA, BswO, fbias);
    conv_a_kernel<<<dim3(MT_TILES * 2, 2), 256, 0, stream>>>(inflat, AswV, query, AswQ, M);
    dual_gemm_kernel<<<MT_TILES * 3, 256, 0, stream>>>((const short8*)AswV, (const short8*)AswQ,
                                                       (const short8*)BswV, (const short8*)BswOA,
                                                       bv, fbias, value, fused, M);
    msda_sample_kernel<<<M / 4, 256, 0, stream>>>(refp, value, fused, AccSw);
    out_gemm_kernel<<<MT_TILES, 256, 0, stream>>>((const short8*)AccSw, (const short8*)BswO,
                                                  bout, out, M);
}

// Round 6
// 231.147 us; speedup vs baseline: 1.0831x; 1.0023x over previous
//
#include <hip/hip_runtime.h>

#define NH 8
#define HD 32
#define NL 4
#define NP 4
#define DM 256
#define LEN_IN_C 13294
#define LQ_C 13294
#define B_C 2
#define M_TOTAL (B_C * LQ_C)           // 26588
#define MT_TILES 1662                  // ceil(26588/16)
#define MT_PAD 1664                    // padded to multiple of 4 row-tiles
#define RBLK (MT_PAD / 4)              // 416 row-blocks of 64 rows

typedef __attribute__((ext_vector_type(8))) short short8;
typedef __attribute__((ext_vector_type(4))) float floatx4;

__device__ __forceinline__ unsigned short f2bf(float x) {
    union { float f; unsigned int u; } a; a.f = x;
    unsigned int r = (a.u + 0x7FFFu + ((a.u >> 16) & 1u)) >> 16;
    return (unsigned short)r;
}
__device__ __forceinline__ float bflo(unsigned int u) {
    union { unsigned int u; float f; } a; a.u = u << 16; return a.f;
}
__device__ __forceinline__ float bfhi(unsigned int u) {
    union { unsigned int u; float f; } a; a.u = u & 0xffff0000u; return a.f;
}

// async global->LDS, 16 B per lane: LDS dest = uniform base + lane*16
__device__ __forceinline__ void glds16(const void* g, void* l) {
    __builtin_amdgcn_global_load_lds(
        (const __attribute__((address_space(1))) unsigned int*)g,
        (__attribute__((address_space(3))) unsigned int*)l, 16, 0, 0);
}

// ---------------------------------------------------------------------------
// Convert A [M,256] fp32 row-major -> swizzled bf16 fragments (padded to
// MT_PAD row-tiles; rows >= M zero-filled).
// Unit u = (rt*8 + kc)*64 + lane; lane = m + 16*q holds A[rt*16+m][kc*32+q*8..+8].
// ---------------------------------------------------------------------------
__global__ __launch_bounds__(256) void conv_a_kernel(const float* __restrict__ A0,
                                                     unsigned short* __restrict__ D0,
                                                     const float* __restrict__ A1,
                                                     unsigned short* __restrict__ D1,
                                                     int M) {
    const float* A = blockIdx.y ? A1 : A0;
    unsigned short* Asw = blockIdx.y ? D1 : D0;
    const int u = blockIdx.x * 256 + threadIdx.x;
    const int lane = u & 63;
    const int kc = (u >> 6) & 7;
    const int rt = u >> 9;
    const int row = rt * 16 + (lane & 15);
    const int col0 = kc * 32 + (lane >> 4) * 8;
    unsigned short tmp[8];
    if (row < M) {
        const float4 f0 = *(const float4*)(A + (size_t)row * 256 + col0);
        const float4 f1 = *(const float4*)(A + (size_t)row * 256 + col0 + 4);
        tmp[0] = f2bf(f0.x); tmp[1] = f2bf(f0.y); tmp[2] = f2bf(f0.z); tmp[3] = f2bf(f0.w);
        tmp[4] = f2bf(f1.x); tmp[5] = f2bf(f1.y); tmp[6] = f2bf(f1.z); tmp[7] = f2bf(f1.w);
    } else {
#pragma unroll
        for (int j = 0; j < 8; ++j) tmp[j] = 0;
    }
    short8 v;
#pragma unroll
    for (int j = 0; j < 8; ++j) v[j] = (short)tmp[j];
    ((short8*)Asw)[u] = v;
}

// ---------------------------------------------------------------------------
// All weight conversions + bias fuse in ONE kernel.
// ---------------------------------------------------------------------------
__device__ __forceinline__ void conv_b_body(const float* __restrict__ W,
                                            unsigned short* __restrict__ Bsw,
                                            int Nsrc, int NTsrc, int NTtotal, int ntOff,
                                            int vblk) {
    const int u = vblk * 256 + threadIdx.x;
    const int lane = u & 63;
    const int unit = u >> 6;
    const int ntl = unit % NTsrc;
    const int kc = unit / NTsrc;
    const int n = ntl * 16 + (lane & 15);
    const int k0 = kc * 32 + (lane >> 4) * 8;
    short8 v;
#pragma unroll
    for (int j = 0; j < 8; ++j)
        v[j] = (short)f2bf(W[(size_t)(k0 + j) * Nsrc + n]);
    ((short8*)Bsw)[(size_t)(kc * NTtotal + ntOff + ntl) * 64 + lane] = v;
}

__global__ __launch_bounds__(256) void conv_weights_kernel(const float* __restrict__ Wv,
                                                           const float* __restrict__ Woff,
                                                           const float* __restrict__ Wattn,
                                                           const float* __restrict__ Wout,
                                                           const float* __restrict__ boff,
                                                           const float* __restrict__ battn,
                                                           unsigned short* __restrict__ BswV,
                                                           unsigned short* __restrict__ BswOA,
                                                           unsigned short* __restrict__ BswO,
                                                           float* __restrict__ fbias) {
    const int blk = blockIdx.x;
    if (blk < 32)        conv_b_body(Wv,    BswV,  256, 16, 16, 0,  blk);
    else if (blk < 64)   conv_b_body(Woff,  BswOA, 256, 16, 24, 0,  blk - 32);
    else if (blk < 80)   conv_b_body(Wattn, BswOA, 128,  8, 24, 16, blk - 64);
    else if (blk < 112)  conv_b_body(Wout,  BswO,  256, 16, 16, 0,  blk - 80);
    else {
        const int t = (blk - 112) * 256 + threadIdx.x;
        if (t < 384) fbias[t] = (t < 256) ? boff[t] : battn[t - 256];
    }
}

// ---------------------------------------------------------------------------
// LDS-staged MFMA GEMM block: 64 rows x 128 cols, full K=256.
//   As: 32 units (4 rt x 8 kc) staged ONCE via async global_load_lds (32 KB).
//   Bs: per-kc slices (8 nt units) double-buffered (2 x 8 KB).
// K-loop: issue next-kc B stage, ds_read a[4]+b[2], 8 MFMAs, barrier.
// Wave w owns local nt units {2w, 2w+1}, all 4 row-tiles.
// ---------------------------------------------------------------------------
template <bool OUT_BF16, int NT_B, int NCOLS>
__device__ __forceinline__ void gemm_lds_body(short8* As, short8* Bs,
                                              const short8* __restrict__ Au,
                                              const short8* __restrict__ Bu,
                                              int rtile0, int ntB,
                                              const float* __restrict__ bias,
                                              void* __restrict__ Cout, int M) {
    const int tid = threadIdx.x;
    const int lane = tid & 63;
    const int wave = tid >> 6;

    // stage A: wave w stages row-tile rtile0+w (8 kc units of 1 KB)
#pragma unroll
    for (int i = 0; i < 8; ++i)
        glds16(&Au[(size_t)((rtile0 + wave) * 8 + i) * 64 + lane], &As[(wave * 8 + i) * 64]);
    // stage B kc=0
#pragma unroll
    for (int j = 0; j < 2; ++j) {
        const int u = wave * 2 + j;
        glds16(&Bu[(size_t)(ntB + u) * 64 + lane], &Bs[u * 64]);
    }
    __syncthreads();

    floatx4 acc[4][2];
#pragma unroll
    for (int r = 0; r < 4; ++r)
#pragma unroll
        for (int j = 0; j < 2; ++j) acc[r][j] = (floatx4){0.f, 0.f, 0.f, 0.f};

#pragma unroll
    for (int kc = 0; kc < 8; ++kc) {
        if (kc < 7) {
#pragma unroll
            for (int j = 0; j < 2; ++j) {
                const int u = wave * 2 + j;
                glds16(&Bu[(size_t)((kc + 1) * NT_B + ntB + u) * 64 + lane],
                       &Bs[(((kc + 1) & 1) * 8 + u) * 64]);
            }
        }
        const short8 a0 = As[(0 * 8 + kc) * 64 + lane];
        const short8 a1 = As[(1 * 8 + kc) * 64 + lane];
        const short8 a2 = As[(2 * 8 + kc) * 64 + lane];
        const short8 a3 = As[(3 * 8 + kc) * 64 + lane];
        const short8 b0 = Bs[((kc & 1) * 8 + wave * 2 + 0) * 64 + lane];
        const short8 b1 = Bs[((kc & 1) * 8 + wave * 2 + 1) * 64 + lane];
        acc[0][0] = __builtin_amdgcn_mfma_f32_16x16x32_bf16(a0, b0, acc[0][0], 0, 0, 0);
        acc[0][1] = __builtin_amdgcn_mfma_f32_16x16x32_bf16(a0, b1, acc[0][1], 0, 0, 0);
        acc[1][0] = __builtin_amdgcn_mfma_f32_16x16x32_bf16(a1, b0, acc[1][0], 0, 0, 0);
        acc[1][1] = __builtin_amdgcn_mfma_f32_16x16x32_bf16(a1, b1, acc[1][1], 0, 0, 0);
        acc[2][0] = __builtin_amdgcn_mfma_f32_16x16x32_bf16(a2, b0, acc[2][0], 0, 0, 0);
        acc[2][1] = __builtin_amdgcn_mfma_f32_16x16x32_bf16(a2, b1, acc[2][1], 0, 0, 0);
        acc[3][0] = __builtin_amdgcn_mfma_f32_16x16x32_bf16(a3, b0, acc[3][0], 0, 0, 0);
        acc[3][1] = __builtin_amdgcn_mfma_f32_16x16x32_bf16(a3, b1, acc[3][1], 0, 0, 0);
        __syncthreads();
    }

    const int colq = lane & 15;
    const int rowq = (lane >> 4) * 4;
#pragma unroll
    for (int j = 0; j < 2; ++j) {
        const int col = (ntB + wave * 2 + j) * 16 + colq;
        const float bc = bias[col];
#pragma unroll
        for (int r = 0; r < 4; ++r) {
#pragma unroll
            for (int reg = 0; reg < 4; ++reg) {
                const int row = (rtile0 + r) * 16 + rowq + reg;
                if (row < M) {
                    const float v = acc[r][j][reg] + bc;
                    if (OUT_BF16)
                        ((unsigned short*)Cout)[(size_t)row * NCOLS + col] = f2bf(v);
                    else
                        ((float*)Cout)[(size_t)row * NCOLS + col] = v;
                }
            }
        }
    }
}

// dual: grid(RBLK, 5). y=0,1: value GEMM colblocks; y=2..4: fused GEMM colblocks.
__global__ __launch_bounds__(256, 3) void dual_gemm_kernel(const short8* __restrict__ AuV,
                                                           const short8* __restrict__ AuQ,
                                                           const short8* __restrict__ BuV,
                                                           const short8* __restrict__ BuOA,
                                                           const float* __restrict__ bv,
                                                           const float* __restrict__ fbias,
                                                           unsigned short* __restrict__ value,
                                                           float* __restrict__ fused, int M) {
    __shared__ short8 As[32 * 64];   // 32 KB
    __shared__ short8 Bs[16 * 64];   // 16 KB
    const int rtile0 = blockIdx.x * 4;
    const int y = blockIdx.y;
    if (y < 2)
        gemm_lds_body<true, 16, 256>(As, Bs, AuV, BuV, rtile0, y * 8, bv, value, M);
    else
        gemm_lds_body<false, 24, 384>(As, Bs, AuQ, BuOA, rtile0, (y - 2) * 8, fbias, fused, M);
}

__global__ __launch_bounds__(256, 3) void out_gemm_kernel(const short8* __restrict__ AuAcc,
                                                          const short8* __restrict__ BuO,
                                                          const float* __restrict__ bout,
                                                          float* __restrict__ out, int M) {
    __shared__ short8 As[32 * 64];
    __shared__ short8 Bs[16 * 64];
    gemm_lds_body<false, 16, 256>(As, Bs, AuAcc, BuO, blockIdx.x * 4, blockIdx.y * 8,
                                  bout, out, M);
}

// ---------------------------------------------------------------------------
// Sampler (unchanged from R5).
// ---------------------------------------------------------------------------
__global__ __launch_bounds__(256, 4) void msda_sample_kernel(const float* __restrict__ refp,
                                                             const unsigned short* __restrict__ value,
                                                             const float* __restrict__ fused,
                                                             unsigned short* __restrict__ AccSw) {
    constexpr int lvl_hw[4] = {100, 50, 25, 13};
    constexpr int lvl_s[4] = {0, 10000, 12500, 13125};

    const int bq0 = blockIdx.x * 4;
    const int tid = threadIdx.x;

    __shared__ float s_ref[32];
    __shared__ int4 s_pi[4 * 8 * 17];
    __shared__ float4 s_pw[4 * 8 * 17];

    if (tid < 32) s_ref[tid] = refp[(size_t)bq0 * 8 + tid];
    __syncthreads();

#pragma unroll
    for (int jj = 0; jj < 2; ++jj) {
        const int job = jj * 256 + tid;
        const int qq = job >> 7;
        const int t = job & 127;
        const int h = t >> 4;
        const int l = (t >> 2) & 3;
        const int bq = bq0 + qq;
        const int b = (bq >= LQ_C) ? 1 : 0;

        const float logit = fused[(size_t)bq * 384 + 256 + t];
        float mx = logit;
#pragma unroll
        for (int mask = 1; mask < 16; mask <<= 1) mx = fmaxf(mx, __shfl_xor(mx, mask));
        const float e = expf(logit - mx);
        float s = e;
#pragma unroll
        for (int mask = 1; mask < 16; mask <<= 1) s += __shfl_xor(s, mask);
        const float aw = e / s;

        const int whl = lvl_hw[l];
        const float fwh = (float)whl;
        const float2 oxy = *(const float2*)(fused + (size_t)bq * 384 + t * 2);
        const float x = s_ref[qq * 8 + l * 2] * fwh + oxy.x - 0.5f;
        const float y = s_ref[qq * 8 + l * 2 + 1] * fwh + oxy.y - 0.5f;
        const float x0f = floorf(x), y0f = floorf(y);
        const float tx = x - x0f, ty = y - y0f;
        const int ix0 = (int)x0f, iy0 = (int)y0f;

        const bool xv0 = (unsigned)ix0 < (unsigned)whl;
        const bool xv1 = (unsigned)(ix0 + 1) < (unsigned)whl;
        const bool yv0 = (unsigned)iy0 < (unsigned)whl;
        const bool yv1 = (unsigned)(iy0 + 1) < (unsigned)whl;

        const int cx0 = min(max(ix0, 0), whl - 1);
        const int cx1 = min(max(ix0 + 1, 0), whl - 1);
        const int cy0 = min(max(iy0, 0), whl - 1);
        const int cy1 = min(max(iy0 + 1, 0), whl - 1);

        const int base = (b * LEN_IN_C + lvl_s[l]) * 256 + h * 32;
        const int r0 = base + cy0 * (whl * 256);
        const int r1 = base + cy1 * (whl * 256);
        int4 ii;
        ii.x = (r0 + cx0 * 256) * 2;
        ii.y = (r0 + cx1 * 256) * 2;
        ii.z = (r1 + cx0 * 256) * 2;
        ii.w = (r1 + cx1 * 256) * 2;
        float4 wv;
        wv.x = (xv0 && yv0) ? aw * (1.f - tx) * (1.f - ty) : 0.f;
        wv.y = (xv1 && yv0) ? aw * tx * (1.f - ty) : 0.f;
        wv.z = (xv0 && yv1) ? aw * (1.f - tx) * ty : 0.f;
        wv.w = (xv1 && yv1) ? aw * tx * ty : 0.f;
        const int slot = (qq * 8 + h) * 17 + (t & 15);
        s_pi[slot] = ii;
        s_pw[slot] = wv;
    }
    __syncthreads();

    const int qq = tid >> 6;
    const int h = (tid >> 3) & 7;
    const int l8 = tid & 7;
    const char* vbp = (const char*)value + l8 * 8;
    const int pbase = (qq * 8 + h) * 17;

    float4 acc0 = {0.f, 0.f, 0.f, 0.f};
    float4 acc1 = {0.f, 0.f, 0.f, 0.f};
#pragma unroll
    for (int g = 0; g < 4; ++g) {
        int4 ii[4]; float4 ww[4]; uint2 v[16];
#pragma unroll
        for (int p = 0; p < 4; ++p) {
            ii[p] = s_pi[pbase + g * 4 + p];
            ww[p] = s_pw[pbase + g * 4 + p];
        }
#pragma unroll
        for (int p = 0; p < 4; ++p) {
            v[p * 4 + 0] = *(const uint2*)(vbp + ii[p].x);
            v[p * 4 + 1] = *(const uint2*)(vbp + ii[p].y);
            v[p * 4 + 2] = *(const uint2*)(vbp + ii[p].z);
            v[p * 4 + 3] = *(const uint2*)(vbp + ii[p].w);
        }
#pragma unroll
        for (int p = 0; p < 4; ++p) {
            const float4 wv = ww[p];
            const uint2 v00 = v[p * 4 + 0], v01 = v[p * 4 + 1];
            const uint2 v10 = v[p * 4 + 2], v11 = v[p * 4 + 3];
            acc0.x += wv.x * bflo(v00.x); acc0.y += wv.x * bfhi(v00.x);
            acc0.z += wv.x * bflo(v00.y); acc0.w += wv.x * bfhi(v00.y);
            acc1.x += wv.y * bflo(v01.x); acc1.y += wv.y * bfhi(v01.x);
            acc1.z += wv.y * bflo(v01.y); acc1.w += wv.y * bfhi(v01.y);
            acc0.x += wv.z * bflo(v10.x); acc0.y += wv.z * bfhi(v10.x);
            acc0.z += wv.z * bflo(v10.y); acc0.w += wv.z * bfhi(v10.y);
            acc1.x += wv.w * bflo(v11.x); acc1.y += wv.w * bfhi(v11.x);
            acc1.z += wv.w * bflo(v11.y); acc1.w += wv.w * bfhi(v11.y);
        }
    }
    const float4 acc = {acc0.x + acc1.x, acc0.y + acc1.y, acc0.z + acc1.z, acc0.w + acc1.w};

    const int bq = bq0 + qq;
    const int rt = bq >> 4, mm = bq & 15;
    const int col = h * 32 + l8 * 4;
    const int kc = col >> 5, q2 = (col >> 3) & 3, j = col & 7;
    unsigned int p0 = (unsigned int)f2bf(acc.x) | ((unsigned int)f2bf(acc.y) << 16);
    unsigned int p1 = (unsigned int)f2bf(acc.z) | ((unsigned int)f2bf(acc.w) << 16);
    uint2 pk; pk.x = p0; pk.y = p1;
    *(uint2*)(AccSw + ((size_t)((rt * 8 + kc) * 64 + (q2 * 16 + mm)) * 8 + j)) = pk;
}

extern "C" void kernel_launch(void* const* d_in, const int* in_sizes, int n_in,
                              void* d_out, int out_size, void* d_ws, size_t ws_size,
                              hipStream_t stream) {
    const float* query  = (const float*)d_in[0];
    const float* refp   = (const float*)d_in[1];
    const float* inflat = (const float*)d_in[2];
    const float* Wv    = (const float*)d_in[4];
    const float* bv    = (const float*)d_in[5];
    const float* Woff  = (const float*)d_in[6];
    const float* boff  = (const float*)d_in[7];
    const float* Wattn = (const float*)d_in[8];
    const float* battn = (const float*)d_in[9];
    const float* Wout  = (const float*)d_in[10];
    const float* bout  = (const float*)d_in[11];
    float* out = (float*)d_out;

    char* p = (char*)d_ws;
    const size_t aswBytes = (size_t)MT_PAD * 8 * 64 * 8 * sizeof(unsigned short); // 13.63 MB
    unsigned short* AswV = (unsigned short*)p;           p += aswBytes;  // value A-frags / AccSw
    unsigned short* AswQ = (unsigned short*)p;           p += aswBytes;
    unsigned short* BswV = (unsigned short*)p;           p += (size_t)8 * 16 * 64 * 8 * 2;
    unsigned short* BswOA = (unsigned short*)p;          p += (size_t)8 * 24 * 64 * 8 * 2;
    unsigned short* BswO = (unsigned short*)p;           p += (size_t)8 * 16 * 64 * 8 * 2;
    float* fbias = (float*)p;                            p += 384 * sizeof(float);
    unsigned short* value = (unsigned short*)p;          p += (size_t)M_TOTAL * 256 * 2;
    float* fused = (float*)p;                            p += (size_t)M_TOTAL * 384 * 4;
    unsigned short* AccSw = AswV;   // alias: dual consumes AswV before sampler writes

    const int M = M_TOTAL;

    conv_weights_kernel<<<114, 256, 0, stream>>>(Wv, Woff, Wattn, Wout, boff, battn,
                                                 BswV, BswOA, BswO, fbias);
    conv_a_kernel<<<dim3(MT_PAD * 2, 2), 256, 0, stream>>>(inflat, AswV, query, AswQ, M);
    dual_gemm_kernel<<<dim3(RBLK, 5), 256, 0, stream>>>((const short8*)AswV, (const short8*)AswQ,
                                                        (const short8*)BswV, (const short8*)BswOA,
                                                        bv, fbias, value, fused, M);
    msda_sample_kernel<<<M / 4, 256, 0, stream>>>(refp, value, fused, AccSw);
    out_gemm_kernel<<<dim3(RBLK, 2), 256, 0, stream>>>((const short8*)AccSw, (const short8*)BswO,
                                                       bout, out, M);
}